// Round 7
// baseline (424.624 us; speedup 1.0000x reference)
//
#include <hip/hip_runtime.h>

#define B_   32
#define C_   16
#define H_   128
#define W_   128
#define HW_  (H_ * W_)
#define NF_  4
#define HID_ 128
#define FIN_ (C_ * NF_)   // 64
#define NPIX (B_ * HW_)   // 524288

// Tiny kernel: W2 [16][128] -> W2t [128][16] so layer-2 weight reads are
// 4 contiguous s_load_dwordx4 per o instead of 16 scattered s_load_dword.
__global__ __launch_bounds__(256) void w2_transpose(
    const float* __restrict__ W2, float* __restrict__ W2t)
{
    int t = blockIdx.x * blockDim.x + threadIdx.x;   // 0..2047
    if (t >= C_ * HID_) return;
    int j = t >> 7;          // row of W2
    int o = t & (HID_ - 1);  // col of W2
    W2t[o * C_ + j] = W2[j * HID_ + o];
}

// Kernel A: depthwise 3x3 circular conv (4 filters) + MLP 64->128->16 +
// masked update. Weights stay on the SCALAR path (wave-uniform indices ->
// s_load into SGPRs; R1's 112-SGPR count proved the compiler does this).
// The ONLY change vs the 278-us R1 baseline: 4 partial accumulators in the
// layer-1 dot (dependent chain 64 -> 16 FMAs; 4-cyc latency now hidden by
// issue), and W2t contiguous rows. No unroll pragmas, no software pipeline
// (R2/R3: both inflated VGPR to 156 and regressed).
__global__ __launch_bounds__(256) void ca_step(
    const float* __restrict__ x,
    const float* __restrict__ rmask,
    const float* __restrict__ filt,
    const float* __restrict__ W1,
    const float* __restrict__ b1,
    const float* __restrict__ W2t,   // transposed [128][16]
    const float* __restrict__ b2,
    float* __restrict__ out,
    float* __restrict__ alpha_new,
    float* __restrict__ pre_life)
{
    int tid = blockIdx.x * blockDim.x + threadIdx.x;
    if (tid >= NPIX) return;
    int b   = tid >> 14;          // / HW_
    int pix = tid & (HW_ - 1);
    int r   = pix >> 7;           // / W_
    int c   = pix & (W_ - 1);

    int rm = (r - 1) & (H_ - 1), rp = (r + 1) & (H_ - 1);
    int cm = (c - 1) & (W_ - 1), cp = (c + 1) & (W_ - 1);
    int off[9] = { rm * W_ + cm, rm * W_ + c, rm * W_ + cp,
                   r  * W_ + cm, r  * W_ + c, r  * W_ + cp,
                   rp * W_ + cm, rp * W_ + c, rp * W_ + cp };

    const float* xb = x + (size_t)b * C_ * HW_;

    float y[FIN_];
    float premax = -1e30f, presum = 0.f;

    #pragma unroll
    for (int ch = 0; ch < C_; ++ch) {
        const float* xc = xb + ch * HW_;
        float n[9];
        #pragma unroll
        for (int t = 0; t < 9; ++t) n[t] = xc[off[t]];
        #pragma unroll
        for (int f = 0; f < NF_; ++f) {
            float a = 0.f;
            #pragma unroll
            for (int t = 0; t < 9; ++t) a = fmaf(filt[f * 9 + t], n[t], a);
            y[ch * NF_ + f] = a;
        }
        if (ch == 3) {
            float mx = n[0], sm = 0.f;
            #pragma unroll
            for (int t = 0; t < 9; ++t) { mx = fmaxf(mx, n[t]); sm += n[t]; }
            premax = mx; presum = sm;
        }
    }
    float pre = (premax > 0.1f && (presum * (1.0f / 9.0f)) < 0.2f) ? 1.f : 0.f;

    // MLP: h = leaky(W1 @ y + b1); dx = W2 @ h + b2
    float acc[C_];
    #pragma unroll
    for (int j = 0; j < C_; ++j) acc[j] = b2[j];

    #pragma unroll 1
    for (int o = 0; o < HID_; ++o) {
        const float* w1r = W1 + o * FIN_;
        float p0 = 0.f, p1 = 0.f, p2 = 0.f, p3 = 0.f;
        #pragma unroll
        for (int k = 0; k < FIN_; k += 4) {
            p0 = fmaf(w1r[k + 0], y[k + 0], p0);
            p1 = fmaf(w1r[k + 1], y[k + 1], p1);
            p2 = fmaf(w1r[k + 2], y[k + 2], p2);
            p3 = fmaf(w1r[k + 3], y[k + 3], p3);
        }
        float t = b1[o] + ((p0 + p1) + (p2 + p3));
        float h = (t >= 0.f) ? t : 0.01f * t;
        const float* w2r = W2t + o * C_;
        #pragma unroll
        for (int j = 0; j < C_; ++j) acc[j] = fmaf(w2r[j], h, acc[j]);
    }

    float um = (rmask[b * HW_ + pix] <= 0.5f) ? 1.f : 0.f;

    float* ob = out + (size_t)b * C_ * HW_ + pix;
    float an = 0.f;
    #pragma unroll
    for (int ch = 0; ch < C_; ++ch) {
        float xv = xb[ch * HW_ + off[4]];
        float xn = xv + acc[ch] * um;
        ob[ch * HW_] = xn;
        if (ch == 3) an = xn;
    }
    alpha_new[tid] = an;
    pre_life[tid]  = pre;
}

// Kernel B: post_life from new alpha plane; zero channels where !(pre & post).
__global__ __launch_bounds__(256) void ca_mask(
    const float* __restrict__ alpha_new,
    const float* __restrict__ pre_life,
    float* __restrict__ out)
{
    int tid = blockIdx.x * blockDim.x + threadIdx.x;
    if (tid >= NPIX) return;
    int b   = tid >> 14;
    int pix = tid & (HW_ - 1);
    int r   = pix >> 7;
    int c   = pix & (W_ - 1);

    int rm = (r - 1) & (H_ - 1), rp = (r + 1) & (H_ - 1);
    int cm = (c - 1) & (W_ - 1), cp = (c + 1) & (W_ - 1);
    int off[9] = { rm * W_ + cm, rm * W_ + c, rm * W_ + cp,
                   r  * W_ + cm, r  * W_ + c, r  * W_ + cp,
                   rp * W_ + cm, rp * W_ + c, rp * W_ + cp };

    const float* ab = alpha_new + (size_t)b * HW_;
    float mx = -1e30f, sm = 0.f;
    #pragma unroll
    for (int t = 0; t < 9; ++t) {
        float v = ab[off[t]];
        mx = fmaxf(mx, v);
        sm += v;
    }
    bool post = (mx > 0.1f) && ((sm * (1.0f / 9.0f)) < 0.2f);
    bool life = post && (pre_life[tid] > 0.5f);
    if (!life) {
        float* ob = out + (size_t)b * C_ * HW_ + pix;
        #pragma unroll
        for (int ch = 0; ch < C_; ++ch) ob[ch * HW_] = 0.f;
    }
}

extern "C" void kernel_launch(void* const* d_in, const int* in_sizes, int n_in,
                              void* d_out, int out_size, void* d_ws, size_t ws_size,
                              hipStream_t stream)
{
    const float* x     = (const float*)d_in[0];
    const float* rmask = (const float*)d_in[1];
    const float* filt  = (const float*)d_in[2];
    const float* W1    = (const float*)d_in[3];
    const float* b1    = (const float*)d_in[4];
    const float* W2    = (const float*)d_in[5];
    const float* b2    = (const float*)d_in[6];
    float* out = (float*)d_out;

    float* alpha_new = (float*)d_ws;           // NPIX floats
    float* pre_life  = alpha_new + NPIX;       // NPIX floats
    float* W2t       = pre_life + NPIX;        // 2048 floats

    w2_transpose<<<dim3(8), dim3(256), 0, stream>>>(W2, W2t);
    ca_step<<<dim3(NPIX / 256), dim3(256), 0, stream>>>(
        x, rmask, filt, W1, b1, W2t, b2, out, alpha_new, pre_life);
    ca_mask<<<dim3(NPIX / 256), dim3(256), 0, stream>>>(alpha_new, pre_life, out);
}

// Round 8
// 212.402 us; speedup vs baseline: 1.9991x; 1.9991x over previous
//
#include <hip/hip_runtime.h>

#define B_   32
#define C_   16
#define H_   128
#define W_   128
#define HW_  (H_ * W_)
#define NF_  4
#define HID_ 128
#define FIN_ (C_ * NF_)   // 64
#define NPIX (B_ * HW_)   // 524288
#define OB_  8            // o-block width (independent FMA chains)

// Tiny kernel: W1 [128][64] -> W1t [64][128], W2 [16][128] -> W2t [128][16].
// Both make the per-iteration weight slices CONTIGUOUS and wave-uniform so
// the compiler emits s_load_dwordx8/x16 into SGPRs (zero VGPR cost; SGPR
// budget structurally limits hoisting -- the R3/R7 VGPR explosion cannot
// happen on the scalar path).
__global__ __launch_bounds__(256) void w_transpose(
    const float* __restrict__ W1, const float* __restrict__ W2,
    float* __restrict__ W1t, float* __restrict__ W2t)
{
    int t = blockIdx.x * blockDim.x + threadIdx.x;
    if (t < HID_ * FIN_) {
        int o = t >> 6;          // 0..127
        int k = t & (FIN_ - 1);  // 0..63
        W1t[k * HID_ + o] = W1[t];
    }
    if (t < C_ * HID_) {
        int j = t >> 7;          // 0..15
        int o = t & (HID_ - 1);  // 0..127
        W2t[o * C_ + j] = W2[t];
    }
}

// Kernel A: depthwise 3x3 circular conv (4 filters) + MLP 64->128->16 +
// masked update. k-outer / o-blocked MLP: per 8-wide o-block, 8 independent
// accumulator chains (distance-8 FMAs -> 16-cyc reissue >> 4-cyc latency),
// weights as contiguous uniform rows -> scalar loads.
__global__ __launch_bounds__(256, 2) void ca_step(
    const float* __restrict__ x,
    const float* __restrict__ rmask,
    const float* __restrict__ filt,
    const float* __restrict__ W1t,   // [64][128]
    const float* __restrict__ b1,
    const float* __restrict__ W2t,   // [128][16]
    const float* __restrict__ b2,
    float* __restrict__ out,
    float* __restrict__ alpha_new,
    float* __restrict__ pre_life)
{
    int tid = blockIdx.x * blockDim.x + threadIdx.x;
    if (tid >= NPIX) return;
    int b   = tid >> 14;          // / HW_
    int pix = tid & (HW_ - 1);
    int r   = pix >> 7;           // / W_
    int c   = pix & (W_ - 1);

    int rm = (r - 1) & (H_ - 1), rp = (r + 1) & (H_ - 1);
    int cm = (c - 1) & (W_ - 1), cp = (c + 1) & (W_ - 1);
    int off[9] = { rm * W_ + cm, rm * W_ + c, rm * W_ + cp,
                   r  * W_ + cm, r  * W_ + c, r  * W_ + cp,
                   rp * W_ + cm, rp * W_ + c, rp * W_ + cp };

    const float* xb = x + (size_t)b * C_ * HW_;

    float y[FIN_];
    float premax = -1e30f, presum = 0.f;

    #pragma unroll
    for (int ch = 0; ch < C_; ++ch) {
        const float* xc = xb + ch * HW_;
        float n[9];
        #pragma unroll
        for (int t = 0; t < 9; ++t) n[t] = xc[off[t]];
        #pragma unroll
        for (int f = 0; f < NF_; ++f) {
            float a = 0.f;
            #pragma unroll
            for (int t = 0; t < 9; ++t) a = fmaf(filt[f * 9 + t], n[t], a);
            y[ch * NF_ + f] = a;
        }
        if (ch == 3) {
            float mx = n[0], sm = 0.f;
            #pragma unroll
            for (int t = 0; t < 9; ++t) { mx = fmaxf(mx, n[t]); sm += n[t]; }
            premax = mx; presum = sm;
        }
    }
    float pre = (premax > 0.1f && (presum * (1.0f / 9.0f)) < 0.2f) ? 1.f : 0.f;

    // MLP: h = leaky(W1 @ y + b1); dx = W2 @ h + b2.
    // ob-loop is a REAL loop (small code, I$-friendly); k/i/j loops fully
    // unrolled so y[]/h[]/acc[] indices are compile-time (rule: runtime-
    // indexed arrays go to scratch).
    float acc[C_];
    #pragma unroll
    for (int j = 0; j < C_; ++j) acc[j] = b2[j];

    #pragma unroll 1
    for (int ob = 0; ob < HID_ / OB_; ++ob) {
        const float* b1p = b1 + ob * OB_;
        float h[OB_];
        #pragma unroll
        for (int i = 0; i < OB_; ++i) h[i] = b1p[i];

        const float* w1b = W1t + ob * OB_;
        #pragma unroll
        for (int k = 0; k < FIN_; ++k) {
            const float* wr = w1b + k * HID_;   // 8 contiguous uniform floats
            float yk = y[k];
            #pragma unroll
            for (int i = 0; i < OB_; ++i) h[i] = fmaf(wr[i], yk, h[i]);
        }

        const float* w2b = W2t + (ob * OB_) * C_;  // 128 contiguous floats
        #pragma unroll
        for (int i = 0; i < OB_; ++i) {
            float t = h[i];
            t = (t >= 0.f) ? t : 0.01f * t;
            #pragma unroll
            for (int j = 0; j < C_; ++j)
                acc[j] = fmaf(w2b[i * C_ + j], t, acc[j]);
        }
    }

    float um = (rmask[b * HW_ + pix] <= 0.5f) ? 1.f : 0.f;

    float* ob_ = out + (size_t)b * C_ * HW_ + pix;
    float an = 0.f;
    #pragma unroll
    for (int ch = 0; ch < C_; ++ch) {
        float xv = xb[ch * HW_ + off[4]];
        float xn = xv + acc[ch] * um;
        ob_[ch * HW_] = xn;
        if (ch == 3) an = xn;
    }
    alpha_new[tid] = an;
    pre_life[tid]  = pre;
}

// Kernel B: post_life from new alpha plane; zero channels where !(pre & post).
__global__ __launch_bounds__(256) void ca_mask(
    const float* __restrict__ alpha_new,
    const float* __restrict__ pre_life,
    float* __restrict__ out)
{
    int tid = blockIdx.x * blockDim.x + threadIdx.x;
    if (tid >= NPIX) return;
    int b   = tid >> 14;
    int pix = tid & (HW_ - 1);
    int r   = pix >> 7;
    int c   = pix & (W_ - 1);

    int rm = (r - 1) & (H_ - 1), rp = (r + 1) & (H_ - 1);
    int cm = (c - 1) & (W_ - 1), cp = (c + 1) & (W_ - 1);
    int off[9] = { rm * W_ + cm, rm * W_ + c, rm * W_ + cp,
                   r  * W_ + cm, r  * W_ + c, r  * W_ + cp,
                   rp * W_ + cm, rp * W_ + c, rp * W_ + cp };

    const float* ab = alpha_new + (size_t)b * HW_;
    float mx = -1e30f, sm = 0.f;
    #pragma unroll
    for (int t = 0; t < 9; ++t) {
        float v = ab[off[t]];
        mx = fmaxf(mx, v);
        sm += v;
    }
    bool post = (mx > 0.1f) && ((sm * (1.0f / 9.0f)) < 0.2f);
    bool life = post && (pre_life[tid] > 0.5f);
    if (!life) {
        float* ob = out + (size_t)b * C_ * HW_ + pix;
        #pragma unroll
        for (int ch = 0; ch < C_; ++ch) ob[ch * HW_] = 0.f;
    }
}

extern "C" void kernel_launch(void* const* d_in, const int* in_sizes, int n_in,
                              void* d_out, int out_size, void* d_ws, size_t ws_size,
                              hipStream_t stream)
{
    const float* x     = (const float*)d_in[0];
    const float* rmask = (const float*)d_in[1];
    const float* filt  = (const float*)d_in[2];
    const float* W1    = (const float*)d_in[3];
    const float* b1    = (const float*)d_in[4];
    const float* W2    = (const float*)d_in[5];
    const float* b2    = (const float*)d_in[6];
    float* out = (float*)d_out;

    float* alpha_new = (float*)d_ws;           // NPIX floats
    float* pre_life  = alpha_new + NPIX;       // NPIX floats
    float* W1t       = pre_life + NPIX;        // 8192 floats
    float* W2t       = W1t + HID_ * FIN_;      // 2048 floats

    w_transpose<<<dim3(32), dim3(256), 0, stream>>>(W1, W2, W1t, W2t);
    ca_step<<<dim3(NPIX / 256), dim3(256), 0, stream>>>(
        x, rmask, filt, W1t, b1, W2t, b2, out, alpha_new, pre_life);
    ca_mask<<<dim3(NPIX / 256), dim3(256), 0, stream>>>(alpha_new, pre_life, out);
}